// Round 3
// 273.009 us; speedup vs baseline: 1.2844x; 1.2844x over previous
//
#include <hip/hip_runtime.h>
#include <hip/hip_bf16.h>

typedef __bf16 bf16_t;
typedef __bf16 bf16x4 __attribute__((ext_vector_type(4)));
typedef __bf16 bf16x8 __attribute__((ext_vector_type(8)));
typedef float f32x4 __attribute__((ext_vector_type(4)));

#define Bb 4
#define Ss 2048
#define Dd 1024
#define Hh 16
#define HDd 64

// attention scale folded into Q at GEMM1 epilogue: 1/8 * log2(e)
#define QSC 0.1803368801111244f

// async global->LDS, 16B per lane. LDS dest must be wave-uniform base + lane*16.
__device__ __forceinline__ void gld16(const bf16_t* g, bf16_t* l) {
  __builtin_amdgcn_global_load_lds(
      (const __attribute__((address_space(1))) unsigned int*)g,
      (__attribute__((address_space(3))) unsigned int*)l, 16, 0, 0);
}

// ------------------------------------------------------------- convert
__global__ __launch_bounds__(256) void conv_to_bf16(
    const float* __restrict__ src, bf16_t* __restrict__ dst) {
  int i = (blockIdx.x * 256 + threadIdx.x) * 4;
  float4 v = *(const float4*)&src[i];
  bf16x4 o = {(bf16_t)v.x, (bf16_t)v.y, (bf16_t)v.z, (bf16_t)v.w};
  *(bf16x4*)&dst[i] = o;
}

// ---------------------------------------------------------------- transpose
// in [R,C] fp32 row-major -> out [C,R] bf16 row-major.
__global__ __launch_bounds__(256) void transpose_conv(
    const float* __restrict__ in, bf16_t* __restrict__ out, int R, int C) {
  __shared__ bf16_t tile[32][33];
  int c0 = blockIdx.x * 32, r0 = blockIdx.y * 32;
  int tx = threadIdx.x, ty = threadIdx.y;  // 32 x 8
#pragma unroll
  for (int j = 0; j < 32; j += 8)
    tile[ty + j][tx] = (bf16_t)in[(size_t)(r0 + ty + j) * C + c0 + tx];
  __syncthreads();
#pragma unroll
  for (int j = 0; j < 32; j += 8)
    out[(size_t)(c0 + ty + j) * R + r0 + tx] = tile[tx][ty + j];
}

// ---------------------------------------------------------------- GEMM
// C[M,N] = A[M,K] @ Bt[N,K]^T + bias. 128x128 tile, m97 structure.
// MODE 0: scatter -> Q*QSC [B,H,S,HD], K [B,H,S,HD], V^T [B,H,HD,S] (bf16).
// MODE 1: plain fp32 row-major store.
template <int MODE>
__global__ __launch_bounds__(256) void gemm_mfma(
    const bf16_t* __restrict__ A, const bf16_t* __restrict__ Bt,
    const float* __restrict__ bias, float* __restrict__ outf,
    bf16_t* __restrict__ out0, bf16_t* __restrict__ out1,
    bf16_t* __restrict__ out2, int M, int N, int K) {
  const int tid = threadIdx.x;
  const int lane = tid & 63;
  const int wave = tid >> 6;
  const int quad = lane >> 4;
  const int lr = lane & 15;
  const int wr = wave >> 1;
  const int wc = wave & 1;
  const int m0 = blockIdx.y * 128;
  const int n0 = blockIdx.x * 128;

  __shared__ __align__(16) bf16_t As[128 * 32];
  __shared__ __align__(16) bf16_t Bs[128 * 32];

  const f32x4 zero = {0.f, 0.f, 0.f, 0.f};
  f32x4 acc[4][4];
#pragma unroll
  for (int mi = 0; mi < 4; ++mi)
#pragma unroll
    for (int ni = 0; ni < 4; ++ni) acc[mi][ni] = zero;

  for (int kt = 0; kt < K; kt += 32) {
#pragma unroll
    for (int i = 0; i < 2; ++i) {
      int chunk = tid + i * 256;        // 0..511
      int row = chunk >> 2;             // 0..127
      int c8 = (chunk & 3) * 8;         // 0,8,16,24
      gld16(&A[(size_t)(m0 + row) * K + kt + c8], &As[chunk * 8]);
      gld16(&Bt[(size_t)(n0 + row) * K + kt + c8], &Bs[chunk * 8]);
    }
    __syncthreads();
    bf16x8 af[4], bfr[4];
    const int k0 = quad * 8;
#pragma unroll
    for (int mi = 0; mi < 4; ++mi)
      af[mi] = *(const bf16x8*)&As[(wr * 64 + mi * 16 + lr) * 32 + k0];
#pragma unroll
    for (int ni = 0; ni < 4; ++ni)
      bfr[ni] = *(const bf16x8*)&Bs[(wc * 64 + ni * 16 + lr) * 32 + k0];
#pragma unroll
    for (int mi = 0; mi < 4; ++mi)
#pragma unroll
      for (int ni = 0; ni < 4; ++ni)
        acc[mi][ni] = __builtin_amdgcn_mfma_f32_16x16x32_bf16(
            af[mi], bfr[ni], acc[mi][ni], 0, 0, 0);
    __syncthreads();
  }

  // Epilogue. C/D layout: col = lane&15, row = quad*4 + r.
#pragma unroll
  for (int mi = 0; mi < 4; ++mi) {
    const int mbase = m0 + wr * 64 + mi * 16 + quad * 4;
#pragma unroll
    for (int ni = 0; ni < 4; ++ni) {
      const int n = n0 + wc * 64 + ni * 16 + lr;
      const float bv = bias[n];
      if (MODE == 1) {
#pragma unroll
        for (int r = 0; r < 4; ++r)
          outf[(size_t)(mbase + r) * N + n] = acc[mi][ni][r] + bv;
      } else {
        const int which = n >> 10;      // uniform per block
        const int h = (n >> 6) & 15;
        const int hd = n & 63;
        const int b = mbase >> 11;
        const int s = mbase & 2047;     // rows mbase..+3 same b
        if (which == 2) {
          // V^T [B,H,HD,S]: 4 consecutive s at fixed hd -> one bf16x4
          bf16x4 pk = {(bf16_t)(acc[mi][ni][0] + bv),
                       (bf16_t)(acc[mi][ni][1] + bv),
                       (bf16_t)(acc[mi][ni][2] + bv),
                       (bf16_t)(acc[mi][ni][3] + bv)};
          *(bf16x4*)&out2[(((size_t)(b * Hh + h)) * HDd + hd) * Ss + s] = pk;
        } else {
          bf16_t* dst = (which == 0) ? out0 : out1;
          const float sc = (which == 0) ? QSC : 1.0f;  // fold attn scale into Q
#pragma unroll
          for (int r = 0; r < 4; ++r)
            dst[(((size_t)(b * Hh + h)) * Ss + s + r) * HDd + hd] =
                (bf16_t)((acc[mi][ni][r] + bv) * sc);
        }
      }
    }
  }
}

// ---------------------------------------------------------------- attention
// Transposed flash attention, no-running-max softmax (scores pre-scaled by
// QSC = log2e/8 via Q; bounded |s|<~3, fp32-safe without max subtraction).
// S^T = K.Q^T, p = 2^s, per-lane l partials, one reduce at end. O^T = V^T.P^T.
//
// Load balance: one block per (bh, pair); pair p processes q-tile (15-p) then
// q-tile p -> every block does exactly 34 k-tile iterations (was 2..32).
// K/V staging double-buffered (global->reg prefetch of tile kt+1 overlaps
// compute on tile kt); ONE barrier per iteration.
// Block->bh mapping groups the 8 pair-blocks of a bh on one XCD (bid%8
// heuristic): 8 bh x 512KB K/V = 4MB = one XCD's L2.
__global__ __launch_bounds__(256) void attn_kernel(
    const bf16_t* __restrict__ Qg, const bf16_t* __restrict__ Kg,
    const bf16_t* __restrict__ Vtg, bf16_t* __restrict__ Og) {
  const int tid = threadIdx.x;
  const int lane = tid & 63;
  const int wave = tid >> 6;
  const int quad = lane >> 4;
  const int lr = lane & 15;

  // bid -> (pair, bh) with all 8 pairs of a bh on the same XCD (bid % 8).
  const int bid = blockIdx.x;        // 0..511
  const int xcd = bid & 7;
  const int j = bid >> 3;            // 0..63
  const int bh = xcd * 8 + (j >> 3); // 8 bh per XCD
  const int p = j & 7;               // pair index 0..7
  const int b = bh >> 4;
  const int h = bh & 15;
  const int wq = wave * 32;

  const bf16_t* Qp = Qg + (size_t)bh * Ss * HDd;   // [s][d] (pre-scaled)
  const bf16_t* Kp = Kg + (size_t)bh * Ss * HDd;   // [s][d]
  const bf16_t* Vp = Vtg + (size_t)bh * HDd * Ss;  // [d][s]

  __shared__ bf16_t Ks[2][64 * 72];    // [buf][key][d]
  __shared__ bf16_t Vts[2][64 * 72];   // [buf][d][key]
  __shared__ bf16_t Ps[4][32 * 72];    // per-wave P [q][key]

  // staging registers: each thread stages 2x16B for K and V
  bf16x8 kreg[2], vreg[2];
  const int r0 = tid >> 3;             // 0..31
  const int c0 = (tid & 7) * 8;        // 0..56

  const f32x4 zero = {0.f, 0.f, 0.f, 0.f};

  // prologue: stage kt=0
#pragma unroll
  for (int i = 0; i < 2; ++i) {
    kreg[i] = *(const bf16x8*)&Kp[(size_t)(r0 + i * 32) * HDd + c0];
    vreg[i] = *(const bf16x8*)&Vp[(size_t)(r0 + i * 32) * Ss + c0];
  }

  int cur = 0;
  for (int half = 0; half < 2; ++half) {
    const int qt = half ? p : 15 - p;
    const int qbase = qt * 128;
    const int ktiles = qt * 2 + 2;

    // Q fragments in registers: B-frag[q-tile][d-chunk]
    bf16x8 bq[2][2];
#pragma unroll
    for (int qt2 = 0; qt2 < 2; ++qt2)
#pragma unroll
      for (int kk2 = 0; kk2 < 2; ++kk2)
        bq[qt2][kk2] = *(const bf16x8*)&Qp[(size_t)(qbase + wq + qt2 * 16 +
                                                    lr) *
                                               HDd +
                                           kk2 * 32 + quad * 8];

    f32x4 oacc[4][2];                  // [d-tile][q-tile], O^T layout
#pragma unroll
    for (int dt = 0; dt < 4; ++dt)
#pragma unroll
      for (int qt2 = 0; qt2 < 2; ++qt2) oacc[dt][qt2] = zero;
    float l_run[2] = {0.f, 0.f};       // per-lane partial sums (no rescale)

    for (int kt = 0; kt < ktiles; ++kt) {
      const int kbase = kt * 64;

      // write staged regs -> LDS[cur]. Safe with one barrier/iter: any wave
      // here has passed last iter's barrier, so no wave is still reading
      // buffer `cur` (last read 2 iters ago, before that barrier).
#pragma unroll
      for (int i = 0; i < 2; ++i) {
        *(bf16x8*)&Ks[cur][(r0 + i * 32) * 72 + c0] = kreg[i];
        *(bf16x8*)&Vts[cur][(r0 + i * 32) * 72 + c0] = vreg[i];
      }
      __syncthreads();

      // prefetch next k-tile (or kt=0 for the next half; harmless extra
      // in-bounds load on the very last iteration)
      const int nkb = (kt + 1 < ktiles) ? kbase + 64 : 0;
#pragma unroll
      for (int i = 0; i < 2; ++i) {
        kreg[i] = *(const bf16x8*)&Kp[(size_t)(nkb + r0 + i * 32) * HDd + c0];
        vreg[i] = *(const bf16x8*)&Vp[(size_t)(r0 + i * 32) * Ss + nkb + c0];
      }

      // S^T tile: sacc[kt4][qt2], row = key = kt4*16+quad*4+r, col = q = lr
      f32x4 sacc[4][2];
#pragma unroll
      for (int kt4 = 0; kt4 < 4; ++kt4)
#pragma unroll
        for (int qt2 = 0; qt2 < 2; ++qt2) sacc[kt4][qt2] = zero;
#pragma unroll
      for (int kk2 = 0; kk2 < 2; ++kk2) {
        bf16x8 ak[4];
#pragma unroll
        for (int kt4 = 0; kt4 < 4; ++kt4)
          ak[kt4] = *(const bf16x8*)&Ks[cur][(kt4 * 16 + lr) * 72 + kk2 * 32 +
                                             quad * 8];
#pragma unroll
        for (int kt4 = 0; kt4 < 4; ++kt4)
#pragma unroll
          for (int qt2 = 0; qt2 < 2; ++qt2)
            sacc[kt4][qt2] = __builtin_amdgcn_mfma_f32_16x16x32_bf16(
                ak[kt4], bq[qt2][kk2], sacc[kt4][qt2], 0, 0, 0);
      }

      // p = 2^s (mask only on the 2 diagonal tiles); accumulate l per-lane
      const bool edge = (kt >= 2 * qt);
#pragma unroll
      for (int kt4 = 0; kt4 < 4; ++kt4)
#pragma unroll
        for (int qt2 = 0; qt2 < 2; ++qt2)
#pragma unroll
          for (int r = 0; r < 4; ++r) {
            float s = sacc[kt4][qt2][r];
            if (edge) {
              const int qg = qbase + wq + qt2 * 16 + lr;
              const int kg = kbase + kt4 * 16 + quad * 4 + r;
              if (kg > qg) s = -1e30f;
            }
            const float pv = __builtin_amdgcn_exp2f(s);
            sacc[kt4][qt2][r] = pv;
            l_run[qt2] += pv;
          }

      // P -> LDS, vectorized: 4 consecutive keys per reg quad
#pragma unroll
      for (int kt4 = 0; kt4 < 4; ++kt4)
#pragma unroll
        for (int qt2 = 0; qt2 < 2; ++qt2) {
          bf16x4 pk = {(bf16_t)sacc[kt4][qt2][0], (bf16_t)sacc[kt4][qt2][1],
                       (bf16_t)sacc[kt4][qt2][2], (bf16_t)sacc[kt4][qt2][3]};
          *(bf16x4*)&Ps[wave][(qt2 * 16 + lr) * 72 + kt4 * 16 + quad * 4] = pk;
        }

      // O^T += V^T.P^T  (same-wave LDS round trip, no barrier needed)
#pragma unroll
      for (int kk2 = 0; kk2 < 2; ++kk2) {
        bf16x8 av[4], bp[2];
#pragma unroll
        for (int dt = 0; dt < 4; ++dt)
          av[dt] = *(const bf16x8*)&Vts[cur][(dt * 16 + lr) * 72 + kk2 * 32 +
                                             quad * 8];
#pragma unroll
        for (int qt2 = 0; qt2 < 2; ++qt2)
          bp[qt2] = *(const bf16x8*)&Ps[wave][(qt2 * 16 + lr) * 72 + kk2 * 32 +
                                              quad * 8];
#pragma unroll
        for (int dt = 0; dt < 4; ++dt)
#pragma unroll
          for (int qt2 = 0; qt2 < 2; ++qt2)
            oacc[dt][qt2] = __builtin_amdgcn_mfma_f32_16x16x32_bf16(
                av[dt], bp[qt2], oacc[dt][qt2], 0, 0, 0);
      }
      cur ^= 1;
    }

    // single l reduction over the quad dimension (lanes +-16, +-32)
#pragma unroll
    for (int qt2 = 0; qt2 < 2; ++qt2) {
      l_run[qt2] += __shfl_xor(l_run[qt2], 16, 64);
      l_run[qt2] += __shfl_xor(l_run[qt2], 32, 64);
    }

    // epilogue: O^T[d][q] -> Og[b][q][h*64+d], 4 contiguous d per store
#pragma unroll
    for (int qt2 = 0; qt2 < 2; ++qt2) {
      const float inv = 1.f / l_run[qt2];
      const int qg = qbase + wq + qt2 * 16 + lr;
#pragma unroll
      for (int dt = 0; dt < 4; ++dt) {
        bf16x4 ov = {(bf16_t)(oacc[dt][qt2][0] * inv),
                     (bf16_t)(oacc[dt][qt2][1] * inv),
                     (bf16_t)(oacc[dt][qt2][2] * inv),
                     (bf16_t)(oacc[dt][qt2][3] * inv)};
        *(bf16x4*)&Og[((size_t)b * Ss + qg) * Dd + h * HDd + dt * 16 +
                      quad * 4] = ov;
      }
    }
  }
}

// ---------------------------------------------------------------- launch
extern "C" void kernel_launch(void* const* d_in, const int* in_sizes, int n_in,
                              void* d_out, int out_size, void* d_ws,
                              size_t ws_size, hipStream_t stream) {
  const float* x = (const float*)d_in[0];       // [4,2048,1024] fp32
  const float* w_qkv = (const float*)d_in[1];   // [1024,3072]
  const float* b_qkv = (const float*)d_in[2];   // [3072]
  const float* w_out = (const float*)d_in[3];   // [1024,1024]
  const float* b_out = (const float*)d_in[4];   // [1024]
  float* out = (float*)d_out;                   // [4,2048,1024] fp32 (32 MB)

  // ws = 48 MB (proven). slot1 Kb (-> Wt2 after attn); slot2 Vt; slot3 Wt1 -> Ob.
  // d_out scratch: Qb [0,16M), Xc bf16 x [16M,32M) — both dead before GEMM2.
  bf16_t* Kb = (bf16_t*)d_ws;                    // [B,H,S,HD]
  bf16_t* Vt = Kb + (size_t)Bb * Hh * Ss * HDd;  // [B,H,HD,S]
  bf16_t* slot3 = Vt + (size_t)Bb * Hh * Ss * HDd;
  bf16_t* Wt1 = slot3;                           // [3072,1024] 6 MB
  bf16_t* Ob = slot3;                            // [8192,1024] 16 MB
  bf16_t* Wt2 = Kb;                              // [1024,1024] 2 MB
  bf16_t* Qb = (bf16_t*)d_out;                   // [B,H,S,HD]
  bf16_t* Xc = (bf16_t*)d_out + (size_t)8192 * 1024;  // [8192,1024] bf16

  conv_to_bf16<<<8192, 256, 0, stream>>>(x, Xc);
  transpose_conv<<<dim3(96, 32), dim3(32, 8), 0, stream>>>(w_qkv, Wt1, 1024,
                                                           3072);

  gemm_mfma<0><<<dim3(24, 64), 256, 0, stream>>>(
      Xc, Wt1, b_qkv, nullptr, Qb, Kb, Vt, 8192, 3072, 1024);

  attn_kernel<<<dim3(512), 256, 0, stream>>>(Qb, Kb, Vt, Ob);

  transpose_conv<<<dim3(32, 32), dim3(32, 8), 0, stream>>>(w_out, Wt2, 1024,
                                                           1024);

  gemm_mfma<1><<<dim3(8, 64), 256, 0, stream>>>(
      Ob, Wt2, b_out, out, nullptr, nullptr, nullptr, 8192, 1024, 1024);
}

// Round 4
// 268.791 us; speedup vs baseline: 1.3045x; 1.0157x over previous
//
#include <hip/hip_runtime.h>
#include <hip/hip_bf16.h>

typedef __bf16 bf16_t;
typedef __bf16 bf16x4 __attribute__((ext_vector_type(4)));
typedef __bf16 bf16x8 __attribute__((ext_vector_type(8)));
typedef float f32x4 __attribute__((ext_vector_type(4)));

#define Bb 4
#define Ss 2048
#define Dd 1024
#define Hh 16
#define HDd 64

// attention scale folded into Q at GEMM1 epilogue: 1/8 * log2(e)
#define QSC 0.1803368801111244f

// async global->LDS, 16B per lane. LDS dest must be wave-uniform base + lane*16.
__device__ __forceinline__ void gld16(const bf16_t* g, bf16_t* l) {
  __builtin_amdgcn_global_load_lds(
      (const __attribute__((address_space(1))) unsigned int*)g,
      (__attribute__((address_space(3))) unsigned int*)l, 16, 0, 0);
}

// ------------------------------------------------------------- convert
__global__ __launch_bounds__(256) void conv_to_bf16(
    const float* __restrict__ src, bf16_t* __restrict__ dst) {
  int i = (blockIdx.x * 256 + threadIdx.x) * 4;
  float4 v = *(const float4*)&src[i];
  bf16x4 o = {(bf16_t)v.x, (bf16_t)v.y, (bf16_t)v.z, (bf16_t)v.w};
  *(bf16x4*)&dst[i] = o;
}

// ---------------------------------------------------------------- transpose
// in [R,C] fp32 row-major -> out [C,R] bf16 row-major.
__global__ __launch_bounds__(256) void transpose_conv(
    const float* __restrict__ in, bf16_t* __restrict__ out, int R, int C) {
  __shared__ bf16_t tile[32][33];
  int c0 = blockIdx.x * 32, r0 = blockIdx.y * 32;
  int tx = threadIdx.x, ty = threadIdx.y;  // 32 x 8
#pragma unroll
  for (int j = 0; j < 32; j += 8)
    tile[ty + j][tx] = (bf16_t)in[(size_t)(r0 + ty + j) * C + c0 + tx];
  __syncthreads();
#pragma unroll
  for (int j = 0; j < 32; j += 8)
    out[(size_t)(c0 + ty + j) * R + r0 + tx] = tile[tx][ty + j];
}

// ---------------------------------------------------------------- GEMM (128x128, m97 structure)
// C[M,N] = A[M,K] @ Bt[N,K]^T + bias. Used for GEMM2 (N=1024: 256-tile grid too small).
// MODE 1: plain fp32 row-major store.
template <int MODE>
__global__ __launch_bounds__(256) void gemm_mfma(
    const bf16_t* __restrict__ A, const bf16_t* __restrict__ Bt,
    const float* __restrict__ bias, float* __restrict__ outf,
    bf16_t* __restrict__ out0, bf16_t* __restrict__ out1,
    bf16_t* __restrict__ out2, int M, int N, int K) {
  const int tid = threadIdx.x;
  const int lane = tid & 63;
  const int wave = tid >> 6;
  const int quad = lane >> 4;
  const int lr = lane & 15;
  const int wr = wave >> 1;
  const int wc = wave & 1;
  const int m0 = blockIdx.y * 128;
  const int n0 = blockIdx.x * 128;

  __shared__ __align__(16) bf16_t As[128 * 32];
  __shared__ __align__(16) bf16_t Bs[128 * 32];

  const f32x4 zero = {0.f, 0.f, 0.f, 0.f};
  f32x4 acc[4][4];
#pragma unroll
  for (int mi = 0; mi < 4; ++mi)
#pragma unroll
    for (int ni = 0; ni < 4; ++ni) acc[mi][ni] = zero;

  for (int kt = 0; kt < K; kt += 32) {
#pragma unroll
    for (int i = 0; i < 2; ++i) {
      int chunk = tid + i * 256;        // 0..511
      int row = chunk >> 2;             // 0..127
      int c8 = (chunk & 3) * 8;         // 0,8,16,24
      gld16(&A[(size_t)(m0 + row) * K + kt + c8], &As[chunk * 8]);
      gld16(&Bt[(size_t)(n0 + row) * K + kt + c8], &Bs[chunk * 8]);
    }
    __syncthreads();
    bf16x8 af[4], bfr[4];
    const int k0 = quad * 8;
#pragma unroll
    for (int mi = 0; mi < 4; ++mi)
      af[mi] = *(const bf16x8*)&As[(wr * 64 + mi * 16 + lr) * 32 + k0];
#pragma unroll
    for (int ni = 0; ni < 4; ++ni)
      bfr[ni] = *(const bf16x8*)&Bs[(wc * 64 + ni * 16 + lr) * 32 + k0];
#pragma unroll
    for (int mi = 0; mi < 4; ++mi)
#pragma unroll
      for (int ni = 0; ni < 4; ++ni)
        acc[mi][ni] = __builtin_amdgcn_mfma_f32_16x16x32_bf16(
            af[mi], bfr[ni], acc[mi][ni], 0, 0, 0);
    __syncthreads();
  }

  // Epilogue. C/D layout: col = lane&15, row = quad*4 + r.
#pragma unroll
  for (int mi = 0; mi < 4; ++mi) {
    const int mbase = m0 + wr * 64 + mi * 16 + quad * 4;
#pragma unroll
    for (int ni = 0; ni < 4; ++ni) {
      const int n = n0 + wc * 64 + ni * 16 + lr;
      const float bv = bias[n];
      if (MODE == 1) {
#pragma unroll
        for (int r = 0; r < 4; ++r)
          outf[(size_t)(mbase + r) * N + n] = acc[mi][ni][r] + bv;
      } else {
        const int which = n >> 10;      // uniform per block
        const int h = (n >> 6) & 15;
        const int hd = n & 63;
        const int b = mbase >> 11;
        const int s = mbase & 2047;     // rows mbase..+3 same b
        if (which == 2) {
          bf16x4 pk = {(bf16_t)(acc[mi][ni][0] + bv),
                       (bf16_t)(acc[mi][ni][1] + bv),
                       (bf16_t)(acc[mi][ni][2] + bv),
                       (bf16_t)(acc[mi][ni][3] + bv)};
          *(bf16x4*)&out2[(((size_t)(b * Hh + h)) * HDd + hd) * Ss + s] = pk;
        } else {
          bf16_t* dst = (which == 0) ? out0 : out1;
          const float sc = (which == 0) ? QSC : 1.0f;
#pragma unroll
          for (int r = 0; r < 4; ++r)
            dst[(((size_t)(b * Hh + h)) * Ss + s + r) * HDd + hd] =
                (bf16_t)((acc[mi][ni][r] + bv) * sc);
        }
      }
    }
  }
}

// ---------------------------------------------------------------- GEMM 256x256, deep pipeline
// T2+T3+T4+T5: 256x256 tile, BK=32 subtiles in a 4-slot LDS ring (128 KiB),
// 8 waves (2M x 4N, per-wave 128x64), 2 phases/subtile (16 MFMA each).
// Stage subtile t+3 while computing t; boundary wait = s_waitcnt vmcnt(8)
// (counted: t+2,t+3's 8 loads stay in flight; t+1 guaranteed landed).
// Ring safety: slot (t+3)&3 was last read in subtile t-1; all reads complete
// before the end-of-(t-1) barrier, and the stage is issued after it (the
// boundary asm-vmcnt is the compiler memory fence anchoring this order).
// LDS swizzle (T2): 16B quarter index XORed with row bits (lr>>1)&3, applied
// by pre-swizzling the GLOBAL source (rule 21: gld_lds dest must be linear)
// and XORing the ds_read quarter. Breaks the 64B-row-stride bank aliasing.
template <int MODE>
__global__ __launch_bounds__(512, 2) void gemm_mfma8(
    const bf16_t* __restrict__ A, const bf16_t* __restrict__ Bt,
    const float* __restrict__ bias, float* __restrict__ outf,
    bf16_t* __restrict__ out0, bf16_t* __restrict__ out1,
    bf16_t* __restrict__ out2, int M, int N, int K) {
  const int tid = threadIdx.x;        // 0..511
  const int lane = tid & 63;
  const int wave = tid >> 6;          // 0..7
  const int quad = lane >> 4;
  const int lr = lane & 15;
  const int wr = wave >> 2;           // 0..1 (M half)
  const int wc = wave & 3;            // 0..3 (N quarter)
  const int m0 = blockIdx.y * 256;
  const int n0 = blockIdx.x * 256;

  __shared__ __align__(16) bf16_t As[4][256 * 32];  // 64 KiB
  __shared__ __align__(16) bf16_t Bs[4][256 * 32];  // 64 KiB

  const f32x4 zero = {0.f, 0.f, 0.f, 0.f};
  f32x4 acc[8][4];
#pragma unroll
  for (int m = 0; m < 8; ++m)
#pragma unroll
    for (int n = 0; n < 4; ++n) acc[m][n] = zero;

  // staging map: linear LDS 16B-chunk c (0..1023): row=c>>2, quarter=c&3.
  // source global quarter = (c&3) ^ ((row>>1)&3)  (XOR involution).
  int srow[2], scol[2];
#pragma unroll
  for (int i = 0; i < 2; ++i) {
    int c = tid + i * 512;
    srow[i] = c >> 2;
    scol[i] = ((c & 3) ^ ((srow[i] >> 1) & 3)) * 8;
  }
  const int nk = K >> 5;

  auto stageA = [&](int t) {
#pragma unroll
    for (int i = 0; i < 2; ++i)
      gld16(&A[(size_t)(m0 + srow[i]) * K + (t << 5) + scol[i]],
            &As[t & 3][(tid + i * 512) * 8]);
  };
  auto stageB = [&](int t) {
#pragma unroll
    for (int i = 0; i < 2; ++i)
      gld16(&Bt[(size_t)(n0 + srow[i]) * K + (t << 5) + scol[i]],
            &Bs[t & 3][(tid + i * 512) * 8]);
  };

  // prologue: 3 subtiles in flight; wait until subtile 0 (oldest 4) landed.
  stageA(0); stageB(0);
  if (nk > 1) { stageA(1); stageB(1); }
  if (nk > 2) { stageA(2); stageB(2); }
  asm volatile("s_waitcnt vmcnt(8)" ::: "memory");
  __builtin_amdgcn_s_barrier();

  const int sw = (lr >> 1) & 3;       // row-derived swizzle for frag reads
  const int qx = (quad ^ sw) * 8;

  for (int t = 0; t < nk; ++t) {
    const bf16_t* as = As[t & 3];
    const bf16_t* bs = Bs[t & 3];
    bf16x8 af[4], bfr[4];
    // ---- phase 0: B-frags + A-frags m0..3, stage A of t+3, 16 MFMA
#pragma unroll
    for (int n = 0; n < 4; ++n)
      bfr[n] = *(const bf16x8*)&bs[(wc * 64 + n * 16 + lr) * 32 + qx];
#pragma unroll
    for (int m = 0; m < 4; ++m)
      af[m] = *(const bf16x8*)&as[(wr * 128 + m * 16 + lr) * 32 + qx];
    if (t + 3 < nk) stageA(t + 3);
    __builtin_amdgcn_s_setprio(1);
#pragma unroll
    for (int m = 0; m < 4; ++m)
#pragma unroll
      for (int n = 0; n < 4; ++n)
        acc[m][n] = __builtin_amdgcn_mfma_f32_16x16x32_bf16(af[m], bfr[n],
                                                            acc[m][n], 0, 0, 0);
    __builtin_amdgcn_s_setprio(0);
    __builtin_amdgcn_s_barrier();
    // ---- phase 1: A-frags m4..7 (B reused), stage B of t+3, 16 MFMA
#pragma unroll
    for (int m = 0; m < 4; ++m)
      af[m] = *(const bf16x8*)&as[(wr * 128 + (m + 4) * 16 + lr) * 32 + qx];
    if (t + 3 < nk) stageB(t + 3);
    __builtin_amdgcn_s_setprio(1);
#pragma unroll
    for (int m = 0; m < 4; ++m)
#pragma unroll
      for (int n = 0; n < 4; ++n)
        acc[m + 4][n] = __builtin_amdgcn_mfma_f32_16x16x32_bf16(
            af[m], bfr[n], acc[m + 4][n], 0, 0, 0);
    __builtin_amdgcn_s_setprio(0);
    // boundary: t+1's loads are older than the newest 8 (t+2, t+3) -> landed.
    asm volatile("s_waitcnt vmcnt(8)" ::: "memory");
    __builtin_amdgcn_s_barrier();
  }

  // Epilogue. C/D layout: col = lane&15, row = quad*4 + r.
#pragma unroll
  for (int mi = 0; mi < 8; ++mi) {
    const int mbase = m0 + wr * 128 + mi * 16 + quad * 4;
#pragma unroll
    for (int ni = 0; ni < 4; ++ni) {
      const int n = n0 + wc * 64 + ni * 16 + lr;
      const float bv = bias[n];
      if (MODE == 1) {
#pragma unroll
        for (int r = 0; r < 4; ++r)
          outf[(size_t)(mbase + r) * N + n] = acc[mi][ni][r] + bv;
      } else {
        const int which = n >> 10;      // uniform per block (256 | 1024)
        const int h = (n >> 6) & 15;
        const int hd = n & 63;
        const int b = mbase >> 11;
        const int s = mbase & 2047;     // rows mbase..+3 same b
        if (which == 2) {
          bf16x4 pk = {(bf16_t)(acc[mi][ni][0] + bv),
                       (bf16_t)(acc[mi][ni][1] + bv),
                       (bf16_t)(acc[mi][ni][2] + bv),
                       (bf16_t)(acc[mi][ni][3] + bv)};
          *(bf16x4*)&out2[(((size_t)(b * Hh + h)) * HDd + hd) * Ss + s] = pk;
        } else {
          bf16_t* dst = (which == 0) ? out0 : out1;
          const float sc = (which == 0) ? QSC : 1.0f;
#pragma unroll
          for (int r = 0; r < 4; ++r)
            dst[(((size_t)(b * Hh + h)) * Ss + s + r) * HDd + hd] =
                (bf16_t)((acc[mi][ni][r] + bv) * sc);
        }
      }
    }
  }
}

// ---------------------------------------------------------------- attention
// Transposed flash attention, no-running-max softmax (scores pre-scaled by
// QSC = log2e/8 via Q; bounded |s|<~3, fp32-safe without max subtraction).
// S^T = K.Q^T, p = 2^s, per-lane l partials, one reduce at end. O^T = V^T.P^T.
// Pair-balanced (34 k-iters/block), double-buffered K/V, bh-per-XCD mapping.
__global__ __launch_bounds__(256) void attn_kernel(
    const bf16_t* __restrict__ Qg, const bf16_t* __restrict__ Kg,
    const bf16_t* __restrict__ Vtg, bf16_t* __restrict__ Og) {
  const int tid = threadIdx.x;
  const int lane = tid & 63;
  const int wave = tid >> 6;
  const int quad = lane >> 4;
  const int lr = lane & 15;

  const int bid = blockIdx.x;        // 0..511
  const int xcd = bid & 7;
  const int j = bid >> 3;            // 0..63
  const int bh = xcd * 8 + (j >> 3); // 8 bh per XCD
  const int p = j & 7;               // pair index 0..7
  const int b = bh >> 4;
  const int h = bh & 15;
  const int wq = wave * 32;

  const bf16_t* Qp = Qg + (size_t)bh * Ss * HDd;   // [s][d] (pre-scaled)
  const bf16_t* Kp = Kg + (size_t)bh * Ss * HDd;   // [s][d]
  const bf16_t* Vp = Vtg + (size_t)bh * HDd * Ss;  // [d][s]

  __shared__ bf16_t Ks[2][64 * 72];    // [buf][key][d]
  __shared__ bf16_t Vts[2][64 * 72];   // [buf][d][key]
  __shared__ bf16_t Ps[4][32 * 72];    // per-wave P [q][key]

  bf16x8 kreg[2], vreg[2];
  const int r0 = tid >> 3;             // 0..31
  const int c0 = (tid & 7) * 8;        // 0..56

  const f32x4 zero = {0.f, 0.f, 0.f, 0.f};

#pragma unroll
  for (int i = 0; i < 2; ++i) {
    kreg[i] = *(const bf16x8*)&Kp[(size_t)(r0 + i * 32) * HDd + c0];
    vreg[i] = *(const bf16x8*)&Vp[(size_t)(r0 + i * 32) * Ss + c0];
  }

  int cur = 0;
  for (int half = 0; half < 2; ++half) {
    const int qt = half ? p : 15 - p;
    const int qbase = qt * 128;
    const int ktiles = qt * 2 + 2;

    bf16x8 bq[2][2];
#pragma unroll
    for (int qt2 = 0; qt2 < 2; ++qt2)
#pragma unroll
      for (int kk2 = 0; kk2 < 2; ++kk2)
        bq[qt2][kk2] = *(const bf16x8*)&Qp[(size_t)(qbase + wq + qt2 * 16 +
                                                    lr) *
                                               HDd +
                                           kk2 * 32 + quad * 8];

    f32x4 oacc[4][2];
#pragma unroll
    for (int dt = 0; dt < 4; ++dt)
#pragma unroll
      for (int qt2 = 0; qt2 < 2; ++qt2) oacc[dt][qt2] = zero;
    float l_run[2] = {0.f, 0.f};

    for (int kt = 0; kt < ktiles; ++kt) {
      const int kbase = kt * 64;

#pragma unroll
      for (int i = 0; i < 2; ++i) {
        *(bf16x8*)&Ks[cur][(r0 + i * 32) * 72 + c0] = kreg[i];
        *(bf16x8*)&Vts[cur][(r0 + i * 32) * 72 + c0] = vreg[i];
      }
      __syncthreads();

      const int nkb = (kt + 1 < ktiles) ? kbase + 64 : 0;
#pragma unroll
      for (int i = 0; i < 2; ++i) {
        kreg[i] = *(const bf16x8*)&Kp[(size_t)(nkb + r0 + i * 32) * HDd + c0];
        vreg[i] = *(const bf16x8*)&Vp[(size_t)(r0 + i * 32) * Ss + nkb + c0];
      }

      f32x4 sacc[4][2];
#pragma unroll
      for (int kt4 = 0; kt4 < 4; ++kt4)
#pragma unroll
        for (int qt2 = 0; qt2 < 2; ++qt2) sacc[kt4][qt2] = zero;
#pragma unroll
      for (int kk2 = 0; kk2 < 2; ++kk2) {
        bf16x8 ak[4];
#pragma unroll
        for (int kt4 = 0; kt4 < 4; ++kt4)
          ak[kt4] = *(const bf16x8*)&Ks[cur][(kt4 * 16 + lr) * 72 + kk2 * 32 +
                                             quad * 8];
#pragma unroll
        for (int kt4 = 0; kt4 < 4; ++kt4)
#pragma unroll
          for (int qt2 = 0; qt2 < 2; ++qt2)
            sacc[kt4][qt2] = __builtin_amdgcn_mfma_f32_16x16x32_bf16(
                ak[kt4], bq[qt2][kk2], sacc[kt4][qt2], 0, 0, 0);
      }

      const bool edge = (kt >= 2 * qt);
#pragma unroll
      for (int kt4 = 0; kt4 < 4; ++kt4)
#pragma unroll
        for (int qt2 = 0; qt2 < 2; ++qt2)
#pragma unroll
          for (int r = 0; r < 4; ++r) {
            float s = sacc[kt4][qt2][r];
            if (edge) {
              const int qg = qbase + wq + qt2 * 16 + lr;
              const int kg = kbase + kt4 * 16 + quad * 4 + r;
              if (kg > qg) s = -1e30f;
            }
            const float pv = __builtin_amdgcn_exp2f(s);
            sacc[kt4][qt2][r] = pv;
            l_run[qt2] += pv;
          }

#pragma unroll
      for (int kt4 = 0; kt4 < 4; ++kt4)
#pragma unroll
        for (int qt2 = 0; qt2 < 2; ++qt2) {
          bf16x4 pk = {(bf16_t)sacc[kt4][qt2][0], (bf16_t)sacc[kt4][qt2][1],
                       (bf16_t)sacc[kt4][qt2][2], (bf16_t)sacc[kt4][qt2][3]};
          *(bf16x4*)&Ps[wave][(qt2 * 16 + lr) * 72 + kt4 * 16 + quad * 4] = pk;
        }

#pragma unroll
      for (int kk2 = 0; kk2 < 2; ++kk2) {
        bf16x8 av[4], bp[2];
#pragma unroll
        for (int dt = 0; dt < 4; ++dt)
          av[dt] = *(const bf16x8*)&Vts[cur][(dt * 16 + lr) * 72 + kk2 * 32 +
                                             quad * 8];
#pragma unroll
        for (int qt2 = 0; qt2 < 2; ++qt2)
          bp[qt2] = *(const bf16x8*)&Ps[wave][(qt2 * 16 + lr) * 72 + kk2 * 32 +
                                              quad * 8];
#pragma unroll
        for (int dt = 0; dt < 4; ++dt)
#pragma unroll
          for (int qt2 = 0; qt2 < 2; ++qt2)
            oacc[dt][qt2] = __builtin_amdgcn_mfma_f32_16x16x32_bf16(
                av[dt], bp[qt2], oacc[dt][qt2], 0, 0, 0);
      }
      cur ^= 1;
    }

#pragma unroll
    for (int qt2 = 0; qt2 < 2; ++qt2) {
      l_run[qt2] += __shfl_xor(l_run[qt2], 16, 64);
      l_run[qt2] += __shfl_xor(l_run[qt2], 32, 64);
    }

#pragma unroll
    for (int qt2 = 0; qt2 < 2; ++qt2) {
      const float inv = 1.f / l_run[qt2];
      const int qg = qbase + wq + qt2 * 16 + lr;
#pragma unroll
      for (int dt = 0; dt < 4; ++dt) {
        bf16x4 ov = {(bf16_t)(oacc[dt][qt2][0] * inv),
                     (bf16_t)(oacc[dt][qt2][1] * inv),
                     (bf16_t)(oacc[dt][qt2][2] * inv),
                     (bf16_t)(oacc[dt][qt2][3] * inv)};
        *(bf16x4*)&Og[((size_t)b * Ss + qg) * Dd + h * HDd + dt * 16 +
                      quad * 4] = ov;
      }
    }
  }
}

// ---------------------------------------------------------------- launch
extern "C" void kernel_launch(void* const* d_in, const int* in_sizes, int n_in,
                              void* d_out, int out_size, void* d_ws,
                              size_t ws_size, hipStream_t stream) {
  const float* x = (const float*)d_in[0];       // [4,2048,1024] fp32
  const float* w_qkv = (const float*)d_in[1];   // [1024,3072]
  const float* b_qkv = (const float*)d_in[2];   // [3072]
  const float* w_out = (const float*)d_in[3];   // [1024,1024]
  const float* b_out = (const float*)d_in[4];   // [1024]
  float* out = (float*)d_out;                   // [4,2048,1024] fp32 (32 MB)

  // ws = 48 MB (proven). slot1 Kb (-> Wt2 after attn); slot2 Vt; slot3 Wt1 -> Ob.
  // d_out scratch: Qb [0,16M), Xc bf16 x [16M,32M) — both dead before GEMM2.
  bf16_t* Kb = (bf16_t*)d_ws;                    // [B,H,S,HD]
  bf16_t* Vt = Kb + (size_t)Bb * Hh * Ss * HDd;  // [B,H,HD,S]
  bf16_t* slot3 = Vt + (size_t)Bb * Hh * Ss * HDd;
  bf16_t* Wt1 = slot3;                           // [3072,1024] 6 MB
  bf16_t* Ob = slot3;                            // [8192,1024] 16 MB
  bf16_t* Wt2 = Kb;                              // [1024,1024] 2 MB
  bf16_t* Qb = (bf16_t*)d_out;                   // [B,H,S,HD]
  bf16_t* Xc = (bf16_t*)d_out + (size_t)8192 * 1024;  // [8192,1024] bf16

  conv_to_bf16<<<8192, 256, 0, stream>>>(x, Xc);
  transpose_conv<<<dim3(96, 32), dim3(32, 8), 0, stream>>>(w_qkv, Wt1, 1024,
                                                           3072);

  gemm_mfma8<0><<<dim3(12, 32), 512, 0, stream>>>(
      Xc, Wt1, b_qkv, nullptr, Qb, Kb, Vt, 8192, 3072, 1024);

  attn_kernel<<<dim3(512), 256, 0, stream>>>(Qb, Kb, Vt, Ob);

  transpose_conv<<<dim3(32, 32), dim3(32, 8), 0, stream>>>(w_out, Wt2, 1024,
                                                           1024);

  gemm_mfma<1><<<dim3(8, 64), 256, 0, stream>>>(
      Ob, Wt2, b_out, out, nullptr, nullptr, nullptr, 8192, 1024, 1024);
}